// Round 9
// baseline (45.863 us; speedup 1.0000x reference)
//
#include <hip/hip_runtime.h>

#define HWSZ 65536                 // 256*256
#define OUT_MAPS (16 * 16 * HWSZ)  // sim_maps element count (16,16,256,256)
#define NBLK 1024                  // main-kernel blocks (2048 row-pair waves / 2)

typedef float fvec4 __attribute__((ext_vector_type(4)));

// Expand one preloaded channel-row (4 px in m) to 6 values incl. halo from
// neighbor lanes. Wave == one image row, lane l holds w = 4l..4l+3.
__device__ __forceinline__ void expand_row(fvec4 m, int lane, float v[6]) {
    float lft = __shfl_up(m.w, 1, 64);
    float rgt = __shfl_down(m.x, 1, 64);
    if (lane == 0)  lft = 0.f;   // w = -1  -> zero pad
    if (lane == 63) rgt = 0.f;   // w = 256 -> zero pad
    v[0] = lft; v[1] = m.x; v[2] = m.y; v[3] = m.z; v[4] = m.w; v[5] = rgt;
}

// Each wave computes TWO adjacent image rows (h0, h0+1); sliding 4-row window
// of inputs shared between them. 128-thread blocks (2 waves): 4 blocks/CU for
// finer scheduling granularity than the 256-thread variant (r8: 2 blocks/CU,
// 12% occupancy, BW-util ~68%). No device fences (r7: ~2x regression).
__global__ __launch_bounds__(128, 4) void sim_main(
    const float* __restrict__ lab,   // (16,3,256,256)
    const float* __restrict__ vec,   // (16,6,256,256)
    float* __restrict__ out,         // (16,16,256,256)
    float* __restrict__ partials)    // NBLK block partial sums
{
    // XCD-aware swizzle (bijective, NBLK=1024): XCD x gets 128 contiguous
    // blocks -> 512 contiguous rows (2 images); vertical-halo re-reads hit
    // the XCD-local L2. Measured FETCH 27.6 -> 18.5 MB (r7/r8).
    const int bs   = ((blockIdx.x & 7) << 7) | (blockIdx.x >> 3);
    const int g    = bs * 128 + threadIdx.x;
    const int lane = threadIdx.x & 63;
    const int wv   = g >> 6;           // global wave id == row-pair id
    const int b    = wv >> 7;          // 128 row-pairs per image
    const int h0   = (wv & 127) << 1;  // even row of the pair
    const int w0   = lane << 2;

    const bool hasU = (h0 > 0);        // wave-uniform
    const bool hasD = (h0 < 254);      // row h0+2 exists (h0+1 always valid)

    // unfold order minus center: (dy,dx)
    constexpr int DY[8] = {-1,-1,-1, 0, 0, 1, 1, 1};
    constexpr int DX[8] = {-1, 0, 1,-1, 1,-1, 0, 1};

    const fvec4 zz = {0.f, 0.f, 0.f, 0.f};

    // ---------- issue ALL loads up front (36 independent row-loads) ----------
    fvec4 L[3][4];   // [c][row h0-1 .. h0+2]  lab
    fvec4 V[6][4];   // [c][row h0-1 .. h0+2]  vec
    {
        const float* pl = lab + b * 3 * HWSZ + h0 * 256 + w0;
        #pragma unroll
        for (int c = 0; c < 3; ++c) {
            L[c][0] = hasU ? *reinterpret_cast<const fvec4*>(pl + c * HWSZ - 256) : zz;
            L[c][1] =        *reinterpret_cast<const fvec4*>(pl + c * HWSZ);
            L[c][2] =        *reinterpret_cast<const fvec4*>(pl + c * HWSZ + 256);
            L[c][3] = hasD ? *reinterpret_cast<const fvec4*>(pl + c * HWSZ + 512) : zz;
        }
        const float* pv = vec + b * 6 * HWSZ + h0 * 256 + w0;
        #pragma unroll
        for (int c = 0; c < 6; ++c) {
            V[c][0] = hasU ? *reinterpret_cast<const fvec4*>(pv + c * HWSZ - 256) : zz;
            V[c][1] =        *reinterpret_cast<const fvec4*>(pv + c * HWSZ);
            V[c][2] =        *reinterpret_cast<const fvec4*>(pv + c * HWSZ + 256);
            V[c][3] = hasD ? *reinterpret_cast<const fvec4*>(pv + c * HWSZ + 512) : zz;
        }
    }

    float accA[8][4], accB[8][4];
    float* ob = out + b * 16 * HWSZ + h0 * 256 + w0;   // row B at ob+256

    // ---------------- lab phase (3 channels, 2 rows) ----------------
    #pragma unroll
    for (int k = 0; k < 8; ++k)
        #pragma unroll
        for (int j = 0; j < 4; ++j) { accA[k][j] = 0.f; accB[k][j] = 0.f; }

    #pragma unroll
    for (int c = 0; c < 3; ++c) {
        float v[4][6];
        #pragma unroll
        for (int r = 0; r < 4; ++r) expand_row(L[c][r], lane, v[r]);
        #pragma unroll
        for (int k = 0; k < 8; ++k) {
            const int r = DY[k] + 1, dx = DX[k];
            #pragma unroll
            for (int j = 0; j < 4; ++j) {
                const float dA = v[1][j + 1] - v[r][j + 1 + dx];
                accA[k][j] = fmaf(dA, dA, accA[k][j]);
                const float dB = v[2][j + 1] - v[r + 1][j + 1 + dx];
                accB[k][j] = fmaf(dB, dB, accB[k][j]);
            }
        }
    }

    unsigned maskA = 0, maskB = 0;   // packed (W_ij >= 0.1) bits, k*4+j
    #pragma unroll
    for (int k = 0; k < 8; ++k) {
        float wA[4], wB[4];
        #pragma unroll
        for (int j = 0; j < 4; ++j) {
            wA[j] = __expf(-__builtin_amdgcn_sqrtf(accA[k][j]));
            wB[j] = __expf(-__builtin_amdgcn_sqrtf(accB[k][j]));
            if (wA[j] >= 0.1f) maskA |= 1u << (k * 4 + j);
            if (wB[j] >= 0.1f) maskB |= 1u << (k * 4 + j);
        }
        fvec4 sA = {wA[0], wA[1], wA[2], wA[3]};
        fvec4 sB = {wB[0], wB[1], wB[2], wB[3]};
        __builtin_nontemporal_store(sA, reinterpret_cast<fvec4*>(ob + k * HWSZ));
        __builtin_nontemporal_store(sB, reinterpret_cast<fvec4*>(ob + k * HWSZ + 256));
    }

    // ---------------- vec phase (6 channels, 2 rows) ----------------
    #pragma unroll
    for (int k = 0; k < 8; ++k)
        #pragma unroll
        for (int j = 0; j < 4; ++j) { accA[k][j] = 0.f; accB[k][j] = 0.f; }

    #pragma unroll
    for (int c = 0; c < 6; ++c) {
        float v[4][6];
        #pragma unroll
        for (int r = 0; r < 4; ++r) expand_row(V[c][r], lane, v[r]);
        #pragma unroll
        for (int k = 0; k < 8; ++k) {
            const int r = DY[k] + 1, dx = DX[k];
            #pragma unroll
            for (int j = 0; j < 4; ++j) {
                const float dA = v[1][j + 1] - v[r][j + 1 + dx];
                accA[k][j] = fmaf(dA, dA, accA[k][j]);
                const float dB = v[2][j + 1] - v[r + 1][j + 1 + dx];
                accB[k][j] = fmaf(dB, dB, accB[k][j]);
            }
        }
    }

    float lsum = 0.f;
    #pragma unroll
    for (int k = 0; k < 8; ++k) {
        float vA[4], vB[4];
        #pragma unroll
        for (int j = 0; j < 4; ++j) {
            vA[j] = __builtin_amdgcn_sqrtf(accA[k][j]);
            vB[j] = __builtin_amdgcn_sqrtf(accB[k][j]);
            if (maskA & (1u << (k * 4 + j))) lsum += vA[j];
            if (maskB & (1u << (k * 4 + j))) lsum += vB[j];
        }
        fvec4 sA = {vA[0], vA[1], vA[2], vA[3]};
        fvec4 sB = {vB[0], vB[1], vB[2], vB[3]};
        __builtin_nontemporal_store(sA, reinterpret_cast<fvec4*>(ob + (8 + k) * HWSZ));
        __builtin_nontemporal_store(sB, reinterpret_cast<fvec4*>(ob + (8 + k) * HWSZ + 256));
    }

    // ---------------- block loss reduction (2 waves) ----------------
    #pragma unroll
    for (int off = 32; off > 0; off >>= 1)
        lsum += __shfl_down(lsum, off, 64);
    __shared__ float ws[2];
    const int wid = threadIdx.x >> 6;
    if (lane == 0) ws[wid] = lsum;
    __syncthreads();
    if (threadIdx.x == 0)
        partials[blockIdx.x] = ws[0] + ws[1];
}

__global__ __launch_bounds__(256) void loss_reduce(
    const float* __restrict__ partials, float* __restrict__ out_loss)
{
    float s = 0.f;
    #pragma unroll
    for (int i = 0; i < NBLK / 256; ++i)
        s += partials[i * 256 + threadIdx.x];
    #pragma unroll
    for (int off = 32; off > 0; off >>= 1)
        s += __shfl_down(s, off, 64);
    __shared__ float ws[4];
    const int lane = threadIdx.x & 63;
    const int wid  = threadIdx.x >> 6;
    if (lane == 0) ws[wid] = s;
    __syncthreads();
    if (threadIdx.x == 0)
        out_loss[0] = (ws[0] + ws[1] + ws[2] + ws[3]) / 8388608.0f;
}

extern "C" void kernel_launch(void* const* d_in, const int* in_sizes, int n_in,
                              void* d_out, int out_size, void* d_ws, size_t ws_size,
                              hipStream_t stream) {
    const float* lab = (const float*)d_in[0];   // images_lab  (16,3,256,256)
    const float* vec = (const float*)d_in[1];   // pixel_vector(16,6,256,256)
    float* out      = (float*)d_out;            // sim_maps (16,16,256,256) + loss
    float* partials = (float*)d_ws;             // NBLK floats

    sim_main<<<NBLK, 128, 0, stream>>>(lab, vec, out, partials);
    loss_reduce<<<1, 256, 0, stream>>>(partials, out + OUT_MAPS);
}

// Round 10
// 23.454 us; speedup vs baseline: 1.9555x; 1.9555x over previous
//
#include <hip/hip_runtime.h>

#define HWSZ 65536                 // 256*256
#define OUT_MAPS (16 * 16 * HWSZ)  // sim_maps element count (16,16,256,256)
#define NBLK 512                   // main-kernel blocks (2048 row-pair waves / 4)

typedef float fvec4 __attribute__((ext_vector_type(4)));

// Expand one preloaded channel-row (4 px in m) to 6 values incl. halo from
// neighbor lanes. Wave == one image row, lane l holds w = 4l..4l+3.
__device__ __forceinline__ void expand_row(fvec4 m, int lane, float v[6]) {
    float lft = __shfl_up(m.w, 1, 64);
    float rgt = __shfl_down(m.x, 1, 64);
    if (lane == 0)  lft = 0.f;   // w = -1  -> zero pad
    if (lane == 63) rgt = 0.f;   // w = 256 -> zero pad
    v[0] = lft; v[1] = m.x; v[2] = m.y; v[3] = m.z; v[4] = m.w; v[5] = rgt;
}

// Each wave computes TWO adjacent image rows (h0, h0+1); sliding 4-row window
// of inputs shared between them. 256-thread blocks, launch_bounds(256,2):
// VGPR budget 256 >= the ~108 this decomposition needs (r9: tighter bounds
// spill -> +105 MB scratch traffic, 2x time). Plain stores this round (A/B
// vs r8's nontemporal). No device fences (r7: ~2x regression).
__global__ __launch_bounds__(256, 2) void sim_main(
    const float* __restrict__ lab,   // (16,3,256,256)
    const float* __restrict__ vec,   // (16,6,256,256)
    float* __restrict__ out,         // (16,16,256,256)
    float* __restrict__ partials)    // NBLK block partial sums
{
    // XCD-aware swizzle (bijective, NBLK=512): XCD x gets 64 contiguous
    // blocks -> 512 contiguous rows (2 images); vertical-halo re-reads hit
    // the XCD-local L2. Measured FETCH 27.6 -> 18.5 MB (r7/r8).
    const int bs   = ((blockIdx.x & 7) << 6) | (blockIdx.x >> 3);
    const int g    = bs * 256 + threadIdx.x;
    const int lane = threadIdx.x & 63;
    const int wv   = g >> 6;           // global wave id == row-pair id
    const int b    = wv >> 7;          // 128 row-pairs per image
    const int h0   = (wv & 127) << 1;  // even row of the pair
    const int w0   = lane << 2;

    const bool hasU = (h0 > 0);        // wave-uniform
    const bool hasD = (h0 < 254);      // row h0+2 exists (h0+1 always valid)

    // unfold order minus center: (dy,dx)
    constexpr int DY[8] = {-1,-1,-1, 0, 0, 1, 1, 1};
    constexpr int DX[8] = {-1, 0, 1,-1, 1,-1, 0, 1};

    const fvec4 zz = {0.f, 0.f, 0.f, 0.f};

    // ---------- issue ALL loads up front (36 independent row-loads) ----------
    fvec4 L[3][4];   // [c][row h0-1 .. h0+2]  lab
    fvec4 V[6][4];   // [c][row h0-1 .. h0+2]  vec
    {
        const float* pl = lab + b * 3 * HWSZ + h0 * 256 + w0;
        #pragma unroll
        for (int c = 0; c < 3; ++c) {
            L[c][0] = hasU ? *reinterpret_cast<const fvec4*>(pl + c * HWSZ - 256) : zz;
            L[c][1] =        *reinterpret_cast<const fvec4*>(pl + c * HWSZ);
            L[c][2] =        *reinterpret_cast<const fvec4*>(pl + c * HWSZ + 256);
            L[c][3] = hasD ? *reinterpret_cast<const fvec4*>(pl + c * HWSZ + 512) : zz;
        }
        const float* pv = vec + b * 6 * HWSZ + h0 * 256 + w0;
        #pragma unroll
        for (int c = 0; c < 6; ++c) {
            V[c][0] = hasU ? *reinterpret_cast<const fvec4*>(pv + c * HWSZ - 256) : zz;
            V[c][1] =        *reinterpret_cast<const fvec4*>(pv + c * HWSZ);
            V[c][2] =        *reinterpret_cast<const fvec4*>(pv + c * HWSZ + 256);
            V[c][3] = hasD ? *reinterpret_cast<const fvec4*>(pv + c * HWSZ + 512) : zz;
        }
    }

    float accA[8][4], accB[8][4];
    float* ob = out + b * 16 * HWSZ + h0 * 256 + w0;   // row B at ob+256

    // ---------------- lab phase (3 channels, 2 rows) ----------------
    #pragma unroll
    for (int k = 0; k < 8; ++k)
        #pragma unroll
        for (int j = 0; j < 4; ++j) { accA[k][j] = 0.f; accB[k][j] = 0.f; }

    #pragma unroll
    for (int c = 0; c < 3; ++c) {
        float v[4][6];
        #pragma unroll
        for (int r = 0; r < 4; ++r) expand_row(L[c][r], lane, v[r]);
        #pragma unroll
        for (int k = 0; k < 8; ++k) {
            const int r = DY[k] + 1, dx = DX[k];
            #pragma unroll
            for (int j = 0; j < 4; ++j) {
                const float dA = v[1][j + 1] - v[r][j + 1 + dx];
                accA[k][j] = fmaf(dA, dA, accA[k][j]);
                const float dB = v[2][j + 1] - v[r + 1][j + 1 + dx];
                accB[k][j] = fmaf(dB, dB, accB[k][j]);
            }
        }
    }

    unsigned maskA = 0, maskB = 0;   // packed (W_ij >= 0.1) bits, k*4+j
    #pragma unroll
    for (int k = 0; k < 8; ++k) {
        float wA[4], wB[4];
        #pragma unroll
        for (int j = 0; j < 4; ++j) {
            wA[j] = __expf(-__builtin_amdgcn_sqrtf(accA[k][j]));
            wB[j] = __expf(-__builtin_amdgcn_sqrtf(accB[k][j]));
            if (wA[j] >= 0.1f) maskA |= 1u << (k * 4 + j);
            if (wB[j] >= 0.1f) maskB |= 1u << (k * 4 + j);
        }
        fvec4 sA = {wA[0], wA[1], wA[2], wA[3]};
        fvec4 sB = {wB[0], wB[1], wB[2], wB[3]};
        *reinterpret_cast<fvec4*>(ob + k * HWSZ)       = sA;
        *reinterpret_cast<fvec4*>(ob + k * HWSZ + 256) = sB;
    }

    // ---------------- vec phase (6 channels, 2 rows) ----------------
    #pragma unroll
    for (int k = 0; k < 8; ++k)
        #pragma unroll
        for (int j = 0; j < 4; ++j) { accA[k][j] = 0.f; accB[k][j] = 0.f; }

    #pragma unroll
    for (int c = 0; c < 6; ++c) {
        float v[4][6];
        #pragma unroll
        for (int r = 0; r < 4; ++r) expand_row(V[c][r], lane, v[r]);
        #pragma unroll
        for (int k = 0; k < 8; ++k) {
            const int r = DY[k] + 1, dx = DX[k];
            #pragma unroll
            for (int j = 0; j < 4; ++j) {
                const float dA = v[1][j + 1] - v[r][j + 1 + dx];
                accA[k][j] = fmaf(dA, dA, accA[k][j]);
                const float dB = v[2][j + 1] - v[r + 1][j + 1 + dx];
                accB[k][j] = fmaf(dB, dB, accB[k][j]);
            }
        }
    }

    float lsum = 0.f;
    #pragma unroll
    for (int k = 0; k < 8; ++k) {
        float vA[4], vB[4];
        #pragma unroll
        for (int j = 0; j < 4; ++j) {
            vA[j] = __builtin_amdgcn_sqrtf(accA[k][j]);
            vB[j] = __builtin_amdgcn_sqrtf(accB[k][j]);
            if (maskA & (1u << (k * 4 + j))) lsum += vA[j];
            if (maskB & (1u << (k * 4 + j))) lsum += vB[j];
        }
        fvec4 sA = {vA[0], vA[1], vA[2], vA[3]};
        fvec4 sB = {vB[0], vB[1], vB[2], vB[3]};
        *reinterpret_cast<fvec4*>(ob + (8 + k) * HWSZ)       = sA;
        *reinterpret_cast<fvec4*>(ob + (8 + k) * HWSZ + 256) = sB;
    }

    // ---------------- block loss reduction ----------------
    #pragma unroll
    for (int off = 32; off > 0; off >>= 1)
        lsum += __shfl_down(lsum, off, 64);
    __shared__ float ws[4];
    const int wid = threadIdx.x >> 6;
    if (lane == 0) ws[wid] = lsum;
    __syncthreads();
    if (threadIdx.x == 0)
        partials[blockIdx.x] = ws[0] + ws[1] + ws[2] + ws[3];
}

__global__ __launch_bounds__(256) void loss_reduce(
    const float* __restrict__ partials, float* __restrict__ out_loss)
{
    float s = 0.f;
    #pragma unroll
    for (int i = 0; i < NBLK / 256; ++i)
        s += partials[i * 256 + threadIdx.x];
    #pragma unroll
    for (int off = 32; off > 0; off >>= 1)
        s += __shfl_down(s, off, 64);
    __shared__ float ws[4];
    const int lane = threadIdx.x & 63;
    const int wid  = threadIdx.x >> 6;
    if (lane == 0) ws[wid] = s;
    __syncthreads();
    if (threadIdx.x == 0)
        out_loss[0] = (ws[0] + ws[1] + ws[2] + ws[3]) / 8388608.0f;
}

extern "C" void kernel_launch(void* const* d_in, const int* in_sizes, int n_in,
                              void* d_out, int out_size, void* d_ws, size_t ws_size,
                              hipStream_t stream) {
    const float* lab = (const float*)d_in[0];   // images_lab  (16,3,256,256)
    const float* vec = (const float*)d_in[1];   // pixel_vector(16,6,256,256)
    float* out      = (float*)d_out;            // sim_maps (16,16,256,256) + loss
    float* partials = (float*)d_ws;             // NBLK floats

    sim_main<<<NBLK, 256, 0, stream>>>(lab, vec, out, partials);
    loss_reduce<<<1, 256, 0, stream>>>(partials, out + OUT_MAPS);
}